// Round 1
// baseline (11745.260 us; speedup 1.0000x reference)
//
#include <hip/hip_runtime.h>
#include <hip/hip_bf16.h>
#include <math.h>

typedef __hip_bfloat16 bf16;

constexpr int kN  = 346;    // nodes
constexpr int kL  = 50;     // seq len
constexpr int kD  = 300;    // emb dim
constexpr int kH  = 300;    // hidden
constexpr int kG  = 1200;   // 4*H
constexpr int kNL = kN * kL; // 17300

__device__ inline float toF(float v) { return v; }
__device__ inline float toF(bf16 v) { return __bfloat162float(v); }
__device__ inline void storeC(float* p, float v) { *p = v; }
__device__ inline void storeC(bf16* p, float v) { *p = __float2bfloat16(v); }
__device__ inline float sigf(float x) { return 1.f / (1.f + expf(-x)); }

// ---------------------------------------------------------------------------
// Generic 64x64 register-tiled GEMM.
// C(MxN) = A(MxK) @ B  where BT=true: B is (N,K) row-major (A@B^T)
//                          BT=false: B is (K,N) row-major (A@B)
// EPI: 0 none, 1 elu, 2 tanh
// ---------------------------------------------------------------------------
template <typename AT, typename CT, bool BT, int EPI>
__global__ void gemm_tile(const AT* __restrict__ A, const float* __restrict__ B,
                          CT* __restrict__ C, int M, int N, int K) {
    __shared__ float As[16][65];
    __shared__ float Bs[16][65];
    int tid = threadIdx.x;
    int tx = tid & 15, ty = tid >> 4;
    int row0 = blockIdx.y * 64, col0 = blockIdx.x * 64;
    float acc[4][4] = {};
    for (int k0 = 0; k0 < K; k0 += 16) {
        for (int i = tid; i < 1024; i += 256) {
            int m = i >> 4, kk = i & 15;
            int gm = row0 + m, gk = k0 + kk;
            As[kk][m] = (gm < M && gk < K) ? toF(A[(size_t)gm * K + gk]) : 0.f;
        }
        if constexpr (BT) {
            for (int i = tid; i < 1024; i += 256) {
                int n = i >> 4, kk = i & 15;
                int gn = col0 + n, gk = k0 + kk;
                Bs[kk][n] = (gn < N && gk < K) ? B[(size_t)gn * K + gk] : 0.f;
            }
        } else {
            for (int i = tid; i < 1024; i += 256) {
                int kk = i >> 6, n = i & 63;
                int gn = col0 + n, gk = k0 + kk;
                Bs[kk][n] = (gn < N && gk < K) ? B[(size_t)gk * N + gn] : 0.f;
            }
        }
        __syncthreads();
#pragma unroll
        for (int kk = 0; kk < 16; ++kk) {
            float a[4], b[4];
#pragma unroll
            for (int u = 0; u < 4; ++u) a[u] = As[kk][ty * 4 + u];
#pragma unroll
            for (int v = 0; v < 4; ++v) b[v] = Bs[kk][tx * 4 + v];
#pragma unroll
            for (int u = 0; u < 4; ++u)
#pragma unroll
                for (int v = 0; v < 4; ++v) acc[u][v] += a[u] * b[v];
        }
        __syncthreads();
    }
#pragma unroll
    for (int u = 0; u < 4; ++u) {
        int gm = row0 + ty * 4 + u;
        if (gm >= M) continue;
#pragma unroll
        for (int v = 0; v < 4; ++v) {
            int gn = col0 + tx * 4 + v;
            if (gn >= N) continue;
            float val = acc[u][v];
            if (EPI == 1) val = val > 0.f ? val : (expf(val) - 1.f);
            if (EPI == 2) val = tanhf(val);
            storeC(&C[(size_t)gm * N + gn], val);
        }
    }
}

// ---------------------------------------------------------------------------
// LSTM recurrent step GEMM: g[dir] = h[dir] @ Whh[dir]^T + P[dir] + bias[dir]
// grid.z = dir (0=f,1=b). M=346, N=1200, K=300.
// ---------------------------------------------------------------------------
__global__ void lstm_gemm(const float* __restrict__ hstate,
                          const float* __restrict__ WhhF, const float* __restrict__ WhhB,
                          const bf16* __restrict__ Pf, const bf16* __restrict__ Pb,
                          const float* __restrict__ bF, const float* __restrict__ bB,
                          float* __restrict__ g) {
    const int M = kN, N = kG, K = kH;
    int dir = blockIdx.z;
    const float* A = hstate + (size_t)dir * kN * kH;
    const float* B = dir ? WhhB : WhhF;
    const bf16* P = dir ? Pb : Pf;
    const float* bias = dir ? bB : bF;
    float* Cout = g + (size_t)dir * kN * kG;

    __shared__ float As[16][65];
    __shared__ float Bs[16][65];
    int tid = threadIdx.x;
    int tx = tid & 15, ty = tid >> 4;
    int row0 = blockIdx.y * 64, col0 = blockIdx.x * 64;
    float acc[4][4] = {};
    for (int k0 = 0; k0 < K; k0 += 16) {
        for (int i = tid; i < 1024; i += 256) {
            int m = i >> 4, kk = i & 15;
            int gm = row0 + m, gk = k0 + kk;
            As[kk][m] = (gm < M && gk < K) ? A[(size_t)gm * K + gk] : 0.f;
        }
        for (int i = tid; i < 1024; i += 256) {
            int n = i >> 4, kk = i & 15;
            int gn = col0 + n, gk = k0 + kk;
            Bs[kk][n] = (gn < N && gk < K) ? B[(size_t)gn * K + gk] : 0.f;
        }
        __syncthreads();
#pragma unroll
        for (int kk = 0; kk < 16; ++kk) {
            float a[4], b[4];
#pragma unroll
            for (int u = 0; u < 4; ++u) a[u] = As[kk][ty * 4 + u];
#pragma unroll
            for (int v = 0; v < 4; ++v) b[v] = Bs[kk][tx * 4 + v];
#pragma unroll
            for (int u = 0; u < 4; ++u)
#pragma unroll
                for (int v = 0; v < 4; ++v) acc[u][v] += a[u] * b[v];
        }
        __syncthreads();
    }
#pragma unroll
    for (int u = 0; u < 4; ++u) {
        int gm = row0 + ty * 4 + u;
        if (gm >= M) continue;
#pragma unroll
        for (int v = 0; v < 4; ++v) {
            int gn = col0 + tx * 4 + v;
            if (gn >= N) continue;
            Cout[(size_t)gm * N + gn] =
                acc[u][v] + toF(P[(size_t)gm * N + gn]) + bias[gn];
        }
    }
}

// gates: i,f,g,o in columns [0:300),[300:600),[600:900),[900:1200)
__global__ void lstm_point(const float* __restrict__ g, float* __restrict__ h,
                           float* __restrict__ c, bf16* __restrict__ o0, int tf, int tb) {
    int idx = blockIdx.x * 256 + threadIdx.x;
    if (idx >= 2 * kN * kH) return;
    int dir = idx / (kN * kH);
    int rem = idx - dir * kN * kH;
    int r = rem / kH, j = rem - r * kH;
    const float* gr = g + (size_t)dir * kN * kG + (size_t)r * kG;
    float iv = sigf(gr[j]);
    float fv = sigf(gr[j + kH]);
    float gv = tanhf(gr[j + 2 * kH]);
    float ov = sigf(gr[j + 3 * kH]);
    float cc = fv * c[idx] + iv * gv;
    c[idx] = cc;
    float hh = ov * tanhf(cc);
    h[idx] = hh;
    if (o0) {
        int t = dir ? tb : tf;
        o0[((size_t)t * kN + r) * (2 * kH) + dir * kH + j] = __float2bfloat16(hh);
    }
}

__global__ void gather_kernel(const int* __restrict__ tokens, const float* __restrict__ emb,
                              bf16* __restrict__ x) {
    int idx = blockIdx.x * 256 + threadIdx.x;
    if (idx >= kNL * kD) return;
    int row = idx / kD, d = idx - row * kD;
    int l = row / kN, n = row - l * kN;
    int tok = tokens[n * kL + l];
    x[idx] = __float2bfloat16(emb[(size_t)tok * kD + d]);
}

__global__ void concat_hs0(const float* __restrict__ h0, const float* __restrict__ h1,
                           float* __restrict__ hs0) {
    int idx = blockIdx.x * 256 + threadIdx.x;
    if (idx >= kN * kG) return;
    int r = idx / kG, c = idx - r * kG;
    float v;
    if (c < 300)       v = h0[(size_t)r * kH + c];
    else if (c < 600)  v = h0[(size_t)(kN + r) * kH + (c - 300)];
    else if (c < 900)  v = h1[(size_t)r * kH + (c - 600)];
    else               v = h1[(size_t)(kN + r) * kH + (c - 900)];
    hs0[idx] = v;
}

__global__ void colsum_kernel(const float* __restrict__ hs, float* __restrict__ sum_hx) {
    int c = blockIdx.x * 256 + threadIdx.x;
    if (c >= kG) return;
    float s = 0.f;
    for (int r = 1; r < kN; ++r) s += hs[(size_t)r * kG + c];
    sum_hx[c] = s;
}

// per-row gate: hin[n] = [hs[n], n==0 ? hs[0] : g*sum_hx + (1-g)*345*hs[0]]
__global__ void gate_rows(const float* __restrict__ hs, const float* __restrict__ gW,
                          const float* __restrict__ gU, const float* __restrict__ sum_hx,
                          bf16* __restrict__ hin) {
    __shared__ float red[256];
    int n = blockIdx.x, tid = threadIdx.x;
    for (int c = tid; c < kG; c += 256)
        hin[(size_t)n * 2400 + c] = __float2bfloat16(hs[(size_t)n * kG + c]);
    if (n == 0) {
        for (int c = tid; c < kG; c += 256)
            hin[1200 + c] = __float2bfloat16(hs[c]);
        return;
    }
    float dw = 0.f, du = 0.f;
    for (int c = tid; c < kG; c += 256) {
        dw += hs[(size_t)n * kG + c] * gW[c];
        du += hs[c] * gU[c];
    }
    red[tid] = dw; __syncthreads();
    for (int s = 128; s > 0; s >>= 1) { if (tid < s) red[tid] += red[tid + s]; __syncthreads(); }
    float sdw = red[0]; __syncthreads();
    red[tid] = du; __syncthreads();
    for (int s = 128; s > 0; s >>= 1) { if (tid < s) red[tid] += red[tid + s]; __syncthreads(); }
    float sdu = red[0]; __syncthreads();
    float gval = sigf(sdw + sdu);
    for (int c = tid; c < kG; c += 256) {
        float v = gval * sum_hx[c] + (1.f - gval) * (345.f * hs[c]);
        hin[(size_t)n * 2400 + 1200 + c] = __float2bfloat16(v);
    }
}

__global__ void gat_scores(const float* __restrict__ Wh, const float* __restrict__ a,
                           float* __restrict__ s1, float* __restrict__ s2) {
    __shared__ float red[256];
    int n = blockIdx.x, tid = threadIdx.x;
    float d1 = 0.f, d2 = 0.f;
    for (int c = tid; c < kG; c += 256) {
        float w = Wh[(size_t)n * kG + c];
        d1 += w * a[c];
        d2 += w * a[kG + c];
    }
    red[tid] = d1; __syncthreads();
    for (int s = 128; s > 0; s >>= 1) { if (tid < s) red[tid] += red[tid + s]; __syncthreads(); }
    if (tid == 0) s1[n] = red[0];
    __syncthreads();
    red[tid] = d2; __syncthreads();
    for (int s = 128; s > 0; s >>= 1) { if (tid < s) red[tid] += red[tid + s]; __syncthreads(); }
    if (tid == 0) s2[n] = red[0];
}

__global__ void gat_softmax(const float* __restrict__ s1, const float* __restrict__ s2,
                            const int* __restrict__ adj, float* __restrict__ att) {
    __shared__ float red[256];
    __shared__ float sh_m, sh_s;
    int i = blockIdx.x, tid = threadIdx.x;
    float s1i = s1[i];
    float m = -1e30f;
    for (int j = tid; j < kN; j += 256) {
        if (adj[i * kN + j] > 0) {
            float e = s1i + s2[j];
            e = e > 0.f ? e : 0.01f * e;
            m = fmaxf(m, e);
        }
    }
    red[tid] = m; __syncthreads();
    for (int s = 128; s > 0; s >>= 1) { if (tid < s) red[tid] = fmaxf(red[tid], red[tid + s]); __syncthreads(); }
    if (tid == 0) sh_m = red[0];
    __syncthreads();
    m = sh_m;
    float sum = 0.f;
    for (int j = tid; j < kN; j += 256) {
        if (adj[i * kN + j] > 0) {
            float e = s1i + s2[j];
            e = e > 0.f ? e : 0.01f * e;
            sum += expf(e - m);
        }
    }
    red[tid] = sum; __syncthreads();
    for (int s = 128; s > 0; s >>= 1) { if (tid < s) red[tid] += red[tid + s]; __syncthreads(); }
    if (tid == 0) sh_s = red[0];
    __syncthreads();
    float inv = sh_s > 0.f ? 1.f / sh_s : 0.f;
    for (int j = tid; j < kN; j += 256) {
        float v = 0.f;
        if (adj[i * kN + j] > 0) {
            float e = s1i + s2[j];
            e = e > 0.f ? e : 0.01f * e;
            v = expf(e - m) * inv;
        }
        att[i * kN + j] = v;
    }
}

__global__ void build_cat4(const float* __restrict__ hs2, bf16* __restrict__ cat4) {
    int idx = blockIdx.x * 256 + threadIdx.x;
    if (idx >= kN * 4800) return;
    int r = idx / 4800, c = idx - r * 4800;
    int chunk = c / kG, cc = c - chunk * kG;
    float hc = hs2[cc];
    float hv = hs2[(size_t)r * kG + cc];
    float v = (chunk == 0) ? hc : (chunk == 1) ? hv : (chunk == 2) ? hc * hv : (hc - hv);
    cat4[idx] = __float2bfloat16(v);
}

__global__ void row_dot_tanh(const float* __restrict__ hc3, const float* __restrict__ FC2,
                             float* __restrict__ b_att) {
    __shared__ float red[256];
    int n = blockIdx.x, tid = threadIdx.x;
    float d = 0.f;
    for (int c = tid; c < 9600; c += 256) d += hc3[(size_t)n * 9600 + c] * FC2[c];
    red[tid] = d; __syncthreads();
    for (int s = 128; s > 0; s >>= 1) { if (tid < s) red[tid] += red[tid + s]; __syncthreads(); }
    if (tid == 0) b_att[n] = tanhf(red[0]);
}

__global__ void ea_kernel(const float* __restrict__ hs2, const float* __restrict__ b_att,
                          float* __restrict__ ea) {
    int c = blockIdx.x * 256 + threadIdx.x;
    if (c >= kG) return;
    float s = 0.f, w = 0.f;
    for (int r = 0; r < kN; ++r) {
        float v = hs2[(size_t)r * kG + c];
        s += v;
        w += b_att[r] * v;
    }
    ea[c] = s / (float)kN;
    ea[kG + c] = w;
}

__global__ void final_kernel(const float* __restrict__ ea, const float* __restrict__ Wlin,
                             const float* __restrict__ blin, float* __restrict__ out) {
    __shared__ float red[256];
    int tid = threadIdx.x;
    float l0 = 0.f, l1 = 0.f;
    for (int c = tid; c < 2400; c += 256) {
        float e = ea[c];
        l0 += e * Wlin[c];
        l1 += e * Wlin[2400 + c];
    }
    red[tid] = l0; __syncthreads();
    for (int s = 128; s > 0; s >>= 1) { if (tid < s) red[tid] += red[tid + s]; __syncthreads(); }
    l0 = red[0]; __syncthreads();
    red[tid] = l1; __syncthreads();
    for (int s = 128; s > 0; s >>= 1) { if (tid < s) red[tid] += red[tid + s]; __syncthreads(); }
    l1 = red[0];
    if (tid == 0) {
        l0 += blin[0];
        l1 += blin[1];
        float m = fmaxf(l0, l1);
        float e0 = expf(l0 - m), e1 = expf(l1 - m);
        float inv = 1.f / (e0 + e1);
        out[0] = e0 * inv;
        out[1] = e1 * inv;
    }
}

// ---------------------------------------------------------------------------
extern "C" void kernel_launch(void* const* d_in, const int* in_sizes, int n_in,
                              void* d_out, int out_size, void* d_ws, size_t ws_size,
                              hipStream_t stream) {
    const int*   tokens  = (const int*)d_in[0];
    const int*   adj     = (const int*)d_in[1];
    const float* emb     = (const float*)d_in[2];
    const float* Wih_l0f = (const float*)d_in[3];
    const float* Whh_l0f = (const float*)d_in[4];
    const float* b_l0f   = (const float*)d_in[5];
    const float* Wih_l0b = (const float*)d_in[6];
    const float* Whh_l0b = (const float*)d_in[7];
    const float* b_l0b   = (const float*)d_in[8];
    const float* Wih_l1f = (const float*)d_in[9];
    const float* Whh_l1f = (const float*)d_in[10];
    const float* b_l1f   = (const float*)d_in[11];
    const float* Wih_l1b = (const float*)d_in[12];
    const float* Whh_l1b = (const float*)d_in[13];
    const float* b_l1b   = (const float*)d_in[14];
    const float* W_gat   = (const float*)d_in[15];
    const float* a_gat   = (const float*)d_in[16];
    const float* gate_W  = (const float*)d_in[17];
    const float* gate_U  = (const float*)d_in[18];
    const float* FC1     = (const float*)d_in[19];
    const float* FC2     = (const float*)d_in[20];
    const float* Wlin    = (const float*)d_in[21];
    const float* blin    = (const float*)d_in[22];
    float* out = (float*)d_out;
    (void)in_sizes; (void)n_in; (void)out_size; (void)ws_size;

    char* base = (char*)d_ws;
    size_t off = 0;
    auto alloc = [&](size_t bytes) {
        size_t cur = off;
        off += (bytes + 255) & ~(size_t)255;
        return cur;
    };

    // Overlay region: [x | P0f | P0b] reused later as [P1f | P1b]
    const size_t x_sz = ((size_t)kNL * kD * 2 + 255) & ~(size_t)255;
    const size_t p_sz = ((size_t)kNL * kG * 2 + 255) & ~(size_t)255;
    size_t r0 = alloc(x_sz + 2 * p_sz);
    bf16* x   = (bf16*)(base + r0);
    bf16* P0f = (bf16*)(base + r0 + x_sz);
    bf16* P0b = (bf16*)(base + r0 + x_sz + p_sz);
    bf16* P1f = (bf16*)(base + r0);          // overlays dead x/P0f
    bf16* P1b = (bf16*)(base + r0 + p_sz);   // overlays dead P0f/P0b

    bf16*  o0     = (bf16*)(base + alloc((size_t)kNL * 600 * 2));
    float* g      = (float*)(base + alloc((size_t)2 * kN * kG * 4));
    float* states = (float*)(base + alloc((size_t)4 * 2 * kN * kH * 4));
    float* h0 = states;
    float* c0 = states + 2 * kN * kH;
    float* h1 = states + 4 * kN * kH;
    float* c1 = states + 6 * kN * kH;
    float* hsA    = (float*)(base + alloc((size_t)kN * kG * 4));
    float* hsB    = (float*)(base + alloc((size_t)kN * kG * 4));
    float* sum_hx = (float*)(base + alloc(kG * 4));
    bf16*  hin    = (bf16*)(base + alloc((size_t)kN * 2400 * 2));
    float* Wh     = (float*)(base + alloc((size_t)kN * kG * 4));
    float* s1     = (float*)(base + alloc(kN * 4));
    float* s2     = (float*)(base + alloc(kN * 4));
    float* att    = (float*)(base + alloc((size_t)kN * kN * 4));
    bf16*  cat4   = (bf16*)(base + alloc((size_t)kN * 4800 * 2));
    float* hc3    = (float*)(base + alloc((size_t)kN * 9600 * 4));
    float* b_att  = (float*)(base + alloc(kN * 4));
    float* ea     = (float*)(base + alloc(2400 * 4));

    // zero LSTM h/c state (ws is poisoned 0xAA before every call)
    hipMemsetAsync(states, 0, (size_t)4 * 2 * kN * kH * 4, stream);

    // embedding gather -> x (L,N,D) bf16
    gather_kernel<<<(kNL * kD + 255) / 256, 256, 0, stream>>>(tokens, emb, x);

    // layer-0 input projections (time-independent)
    dim3 gP((kG + 63) / 64, (kNL + 63) / 64);
    gemm_tile<bf16, bf16, true, 0><<<gP, 256, 0, stream>>>(x, Wih_l0f, P0f, kNL, kG, kD);
    gemm_tile<bf16, bf16, true, 0><<<gP, 256, 0, stream>>>(x, Wih_l0b, P0b, kNL, kG, kD);

    // layer-0 scan (fwd t ascending, bwd t descending, fused per step)
    dim3 gS((kG + 63) / 64, (kN + 63) / 64, 2);
    int ptBlocks = (2 * kN * kH + 255) / 256;
    for (int t = 0; t < kL; ++t) {
        lstm_gemm<<<gS, 256, 0, stream>>>(h0, Whh_l0f, Whh_l0b,
            P0f + (size_t)t * kN * kG, P0b + (size_t)(kL - 1 - t) * kN * kG,
            b_l0f, b_l0b, g);
        lstm_point<<<ptBlocks, 256, 0, stream>>>(g, h0, c0, o0, t, kL - 1 - t);
    }

    // layer-1 input projections from o0
    gemm_tile<bf16, bf16, true, 0><<<gP, 256, 0, stream>>>(o0, Wih_l1f, P1f, kNL, kG, 2 * kH);
    gemm_tile<bf16, bf16, true, 0><<<gP, 256, 0, stream>>>(o0, Wih_l1b, P1b, kNL, kG, 2 * kH);

    // layer-1 scan (only final hidden states needed)
    for (int t = 0; t < kL; ++t) {
        lstm_gemm<<<gS, 256, 0, stream>>>(h1, Whh_l1f, Whh_l1b,
            P1f + (size_t)t * kN * kG, P1b + (size_t)(kL - 1 - t) * kN * kG,
            b_l1f, b_l1b, g);
        lstm_point<<<ptBlocks, 256, 0, stream>>>(g, h1, c1, (bf16*)nullptr, t, kL - 1 - t);
    }

    // hs0 = [hf0, hb0, hf1, hb1]
    concat_hs0<<<(kN * kG + 255) / 256, 256, 0, stream>>>(h0, h1, hsA);

    // two gated-GAT layers
    float* hsIn = hsA;
    float* hsOut = hsB;
    dim3 gW((kG + 63) / 64, (kN + 63) / 64);
    for (int it = 0; it < 2; ++it) {
        colsum_kernel<<<(kG + 255) / 256, 256, 0, stream>>>(hsIn, sum_hx);
        gate_rows<<<kN, 256, 0, stream>>>(hsIn, gate_W, gate_U, sum_hx, hin);
        gemm_tile<bf16, float, false, 0><<<gW, 256, 0, stream>>>(hin, W_gat, Wh, kN, kG, 2400);
        gat_scores<<<kN, 256, 0, stream>>>(Wh, a_gat, s1, s2);
        gat_softmax<<<kN, 256, 0, stream>>>(s1, s2, adj, att);
        gemm_tile<float, float, false, 1><<<gW, 256, 0, stream>>>(att, Wh, hsOut, kN, kG, kN);
        float* tmp = hsIn; hsIn = hsOut; hsOut = tmp;
    }
    // hs2 = hsIn

    // head
    build_cat4<<<(kN * 4800 + 255) / 256, 256, 0, stream>>>(hsIn, cat4);
    dim3 gF((9600 + 63) / 64, (kN + 63) / 64);
    gemm_tile<bf16, float, false, 2><<<gF, 256, 0, stream>>>(cat4, FC1, hc3, kN, 9600, 4800);
    row_dot_tanh<<<kN, 256, 0, stream>>>(hc3, FC2, b_att);
    ea_kernel<<<(kG + 255) / 256, 256, 0, stream>>>(hsIn, b_att, ea);
    final_kernel<<<1, 256, 0, stream>>>(ea, Wlin, blin, out);
}

// Round 2
// 4399.990 us; speedup vs baseline: 2.6694x; 2.6694x over previous
//
#include <hip/hip_runtime.h>
#include <hip/hip_bf16.h>
#include <math.h>

typedef __hip_bfloat16 bf16;
typedef __attribute__((ext_vector_type(8))) short bf16x8;
typedef __attribute__((ext_vector_type(4))) float f32x4;

constexpr int kN  = 346;     // nodes
constexpr int kL  = 50;      // seq len
constexpr int kD  = 300;     // emb dim
constexpr int kH  = 300;     // hidden
constexpr int kG  = 1200;    // 4*H
constexpr int kNL = kN * kL; // 17300
constexpr int kNLp = 17408;  // kNL padded to 128
constexpr int kNp  = 384;    // kN padded to 128
constexpr int kKp0 = 320;    // K=300 padded to 32
constexpr int kKp1 = 608;    // K=600 padded to 32
constexpr int kGp  = 1280;   // N=1200 padded to 128

__device__ inline float toF(float v) { return v; }
__device__ inline float toF(bf16 v) { return __bfloat162float(v); }
__device__ inline void storeC(float* p, float v) { *p = v; }
__device__ inline void storeC(bf16* p, float v) { *p = __float2bfloat16(v); }
__device__ inline float sigf(float x) { return 1.f / (1.f + expf(-x)); }

// ---------------------------------------------------------------------------
// MFMA GEMM: C(MxN) = A(MxK) @ B^T where A is (Mpad x lda) bf16 K-contiguous,
// B is (Npad x ldb) bf16 K-contiguous (i.e. B stored transposed, (N,K)).
// K must be a multiple of 32; A rows padded to gridDim.y*128, B rows padded to
// gridDim.x*128, K-pads zero-filled. Only C store is guarded by M,N.
// EPI: 0 plain, 1 +P(bf16)+bias, 3 elu, 4 tanh
// ---------------------------------------------------------------------------
template <int EPI, typename CT>
__global__ __launch_bounds__(256) void gemm_mfma(
    const bf16* __restrict__ A, const bf16* __restrict__ B, CT* __restrict__ C,
    int M, int N, int K, int lda, int ldb, int ldc,
    long sAz, long sBz, long sCz,
    const bf16* __restrict__ P, long sPz, const float* __restrict__ bias, long sbz)
{
    const short* Ag = (const short*)A + (size_t)blockIdx.z * sAz;
    const short* Bg = (const short*)B + (size_t)blockIdx.z * sBz;
    CT* Cg = C + (size_t)blockIdx.z * sCz;
    const bf16* Pg = nullptr; const float* bg = nullptr;
    if constexpr (EPI == 1) { Pg = P + (size_t)blockIdx.z * sPz; bg = bias + (size_t)blockIdx.z * sbz; }

    __shared__ short As[128 * 40];   // row stride 40 (80B) -> 2-way LDS aliasing (free)
    __shared__ short Bs[128 * 40];
    int tid = threadIdx.x;
    int row0 = blockIdx.y * 128, col0 = blockIdx.x * 128;
    int wave = tid >> 6, lane = tid & 63;
    int wr = (wave >> 1) * 64, wc = (wave & 1) * 64;
    int lrow = lane & 15, lq = lane >> 4;

    f32x4 acc[4][4];
#pragma unroll
    for (int i = 0; i < 4; ++i)
#pragma unroll
        for (int j = 0; j < 4; ++j) acc[i][j] = (f32x4){0.f, 0.f, 0.f, 0.f};

    int sr = tid >> 2;          // 0..63
    int sc = (tid & 3) * 8;     // 0,8,16,24
    for (int k0 = 0; k0 < K; k0 += 32) {
        *(bf16x8*)&As[sr * 40 + sc]        = *(const bf16x8*)&Ag[(size_t)(row0 + sr) * lda + k0 + sc];
        *(bf16x8*)&As[(sr + 64) * 40 + sc] = *(const bf16x8*)&Ag[(size_t)(row0 + sr + 64) * lda + k0 + sc];
        *(bf16x8*)&Bs[sr * 40 + sc]        = *(const bf16x8*)&Bg[(size_t)(col0 + sr) * ldb + k0 + sc];
        *(bf16x8*)&Bs[(sr + 64) * 40 + sc] = *(const bf16x8*)&Bg[(size_t)(col0 + sr + 64) * ldb + k0 + sc];
        __syncthreads();
        bf16x8 aF[4], bF[4];
#pragma unroll
        for (int i = 0; i < 4; ++i) aF[i] = *(const bf16x8*)&As[(wr + i * 16 + lrow) * 40 + lq * 8];
#pragma unroll
        for (int j = 0; j < 4; ++j) bF[j] = *(const bf16x8*)&Bs[(wc + j * 16 + lrow) * 40 + lq * 8];
#pragma unroll
        for (int i = 0; i < 4; ++i)
#pragma unroll
            for (int j = 0; j < 4; ++j)
                acc[i][j] = __builtin_amdgcn_mfma_f32_16x16x32_bf16(aF[i], bF[j], acc[i][j], 0, 0, 0);
        __syncthreads();
    }
    // epilogue: C/D layout col=lane&15, row=(lane>>4)*4+reg [m89/m91 verified]
#pragma unroll
    for (int i = 0; i < 4; ++i) {
#pragma unroll
        for (int r = 0; r < 4; ++r) {
            int gm = row0 + wr + i * 16 + lq * 4 + r;
            if (gm >= M) continue;
#pragma unroll
            for (int j = 0; j < 4; ++j) {
                int gn = col0 + wc + j * 16 + lrow;
                if (gn >= N) continue;
                float v = acc[i][j][r];
                if constexpr (EPI == 1) v += toF(Pg[(size_t)gm * ldc + gn]) + bg[gn];
                if constexpr (EPI == 3) v = v > 0.f ? v : (expf(v) - 1.f);
                if constexpr (EPI == 4) v = tanhf(v);
                storeC(&Cg[(size_t)gm * ldc + gn], v);
            }
        }
    }
}

// fp32 (R x Cc) row-major -> bf16 (Cpad x Rpad) transposed, zero-padded
__global__ void transpose_conv(const float* __restrict__ in, bf16* __restrict__ out,
                               int R, int Cc, int Rpad, int Cpad) {
    __shared__ float tile[32][33];
    int bc = blockIdx.x * 32, br = blockIdx.y * 32;
    int tx = threadIdx.x & 31, ty = threadIdx.x >> 5;  // 32x8
#pragma unroll
    for (int k = 0; k < 4; ++k) {
        int r = br + ty + 8 * k, c = bc + tx;
        tile[ty + 8 * k][tx] = (r < R && c < Cc) ? in[(size_t)r * Cc + c] : 0.f;
    }
    __syncthreads();
#pragma unroll
    for (int k = 0; k < 4; ++k) {
        int c = bc + ty + 8 * k, r = br + tx;
        if (c < Cpad && r < Rpad) out[(size_t)c * Rpad + r] = __float2bfloat16(tile[tx][ty + 8 * k]);
    }
}

// fp32 (R x Cc) -> bf16 (Rpad x Cpad) same layout, zero-padded
__global__ void convert_pad(const float* __restrict__ in, bf16* __restrict__ out,
                            int R, int Cc, int Rpad, int Cpad) {
    int idx = blockIdx.x * 256 + threadIdx.x;
    if (idx >= Rpad * Cpad) return;
    int r = idx / Cpad, c = idx - r * Cpad;
    float v = (r < R && c < Cc) ? in[(size_t)r * Cc + c] : 0.f;
    out[idx] = __float2bfloat16(v);
}

__global__ void pack_biases(const float* b0f, const float* b0b, const float* b1f,
                            const float* b1b, float* b0, float* b1) {
    int i = blockIdx.x * 256 + threadIdx.x;
    if (i < 1200) { b0[i] = b0f[i]; b1[i] = b1f[i]; }
    else if (i < 2400) { b0[i] = b0b[i - 1200]; b1[i] = b1b[i - 1200]; }
}

// embedding gather -> xPad (kNLp x kKp0) bf16, zero pads
__global__ void gather_kernel(const int* __restrict__ tokens, const float* __restrict__ emb,
                              bf16* __restrict__ x) {
    int idx = blockIdx.x * 256 + threadIdx.x;
    if (idx >= kNLp * kKp0) return;
    int row = idx / kKp0, d = idx - row * kKp0;
    float v = 0.f;
    if (row < kNL && d < kD) {
        int l = row / kN, n = row - l * kN;
        v = emb[(size_t)tokens[n * kL + l] * kD + d];
    }
    x[idx] = __float2bfloat16(v);
}

// gates i,f,g,o in cols [0:300),[300:600),[600:900),[900:1200)
__global__ void lstm_point(const float* __restrict__ g, float* __restrict__ c,
                           bf16* __restrict__ hbf, bf16* __restrict__ o0, int tf, int tb) {
    int idx = blockIdx.x * 256 + threadIdx.x;
    if (idx >= 2 * kN * kH) return;
    int dir = idx / (kN * kH);
    int rem = idx - dir * kN * kH;
    int r = rem / kH, j = rem - r * kH;
    const float* gr = g + (size_t)dir * kN * kG + (size_t)r * kG;
    float iv = sigf(gr[j]);
    float fv = sigf(gr[j + kH]);
    float gv = tanhf(gr[j + 2 * kH]);
    float ov = sigf(gr[j + 3 * kH]);
    float cc = fv * c[idx] + iv * gv;
    c[idx] = cc;
    float hh = ov * tanhf(cc);
    hbf[(size_t)dir * kNp * kKp0 + (size_t)r * kKp0 + j] = __float2bfloat16(hh);
    if (o0) {
        int t = dir ? tb : tf;
        o0[(size_t)(t * kN + r) * kKp1 + dir * kH + j] = __float2bfloat16(hh);
    }
}

__global__ void concat_hs0(const bf16* __restrict__ hbf0, const bf16* __restrict__ hbf1,
                           float* __restrict__ hs0) {
    int idx = blockIdx.x * 256 + threadIdx.x;
    if (idx >= kN * kG) return;
    int r = idx / kG, c = idx - r * kG;
    float v;
    if (c < 300)       v = toF(hbf0[(size_t)r * kKp0 + c]);
    else if (c < 600)  v = toF(hbf0[(size_t)(kNp + r) * kKp0 + (c - 300)]);
    else if (c < 900)  v = toF(hbf1[(size_t)r * kKp0 + (c - 600)]);
    else               v = toF(hbf1[(size_t)(kNp + r) * kKp0 + (c - 900)]);
    hs0[idx] = v;
}

__global__ void colsum_kernel(const float* __restrict__ hs, float* __restrict__ sum_hx) {
    int c = blockIdx.x * 256 + threadIdx.x;
    if (c >= kG) return;
    float s = 0.f;
    for (int r = 1; r < kN; ++r) s += hs[(size_t)r * kG + c];
    sum_hx[c] = s;
}

// hin[n] = [hs[n], n==0 ? hs[0] : g*sum_hx + (1-g)*345*hs[0]]  (bf16, lda 2400)
__global__ void gate_rows(const float* __restrict__ hs, const float* __restrict__ gW,
                          const float* __restrict__ gU, const float* __restrict__ sum_hx,
                          bf16* __restrict__ hin) {
    __shared__ float red[256];
    int n = blockIdx.x, tid = threadIdx.x;
    for (int c = tid; c < kG; c += 256)
        hin[(size_t)n * 2400 + c] = __float2bfloat16(hs[(size_t)n * kG + c]);
    if (n == 0) {
        for (int c = tid; c < kG; c += 256)
            hin[1200 + c] = __float2bfloat16(hs[c]);
        return;
    }
    float dw = 0.f, du = 0.f;
    for (int c = tid; c < kG; c += 256) {
        dw += hs[(size_t)n * kG + c] * gW[c];
        du += hs[c] * gU[c];
    }
    red[tid] = dw; __syncthreads();
    for (int s = 128; s > 0; s >>= 1) { if (tid < s) red[tid] += red[tid + s]; __syncthreads(); }
    float sdw = red[0]; __syncthreads();
    red[tid] = du; __syncthreads();
    for (int s = 128; s > 0; s >>= 1) { if (tid < s) red[tid] += red[tid + s]; __syncthreads(); }
    float sdu = red[0]; __syncthreads();
    float gval = sigf(sdw + sdu);
    for (int c = tid; c < kG; c += 256) {
        float v = gval * sum_hx[c] + (1.f - gval) * (345.f * hs[c]);
        hin[(size_t)n * 2400 + 1200 + c] = __float2bfloat16(v);
    }
}

__global__ void gat_scores(const float* __restrict__ Wh, const float* __restrict__ a,
                           float* __restrict__ s1, float* __restrict__ s2) {
    __shared__ float red[256];
    int n = blockIdx.x, tid = threadIdx.x;
    float d1 = 0.f, d2 = 0.f;
    for (int c = tid; c < kG; c += 256) {
        float w = Wh[(size_t)n * kG + c];
        d1 += w * a[c];
        d2 += w * a[kG + c];
    }
    red[tid] = d1; __syncthreads();
    for (int s = 128; s > 0; s >>= 1) { if (tid < s) red[tid] += red[tid + s]; __syncthreads(); }
    if (tid == 0) s1[n] = red[0];
    __syncthreads();
    red[tid] = d2; __syncthreads();
    for (int s = 128; s > 0; s >>= 1) { if (tid < s) red[tid] += red[tid + s]; __syncthreads(); }
    if (tid == 0) s2[n] = red[0];
}

// att row i (bf16, lda 352); pads kept zero by pre-memset
__global__ void gat_softmax(const float* __restrict__ s1, const float* __restrict__ s2,
                            const int* __restrict__ adj, bf16* __restrict__ att) {
    __shared__ float red[256];
    __shared__ float sh_m, sh_s;
    int i = blockIdx.x, tid = threadIdx.x;
    float s1i = s1[i];
    float m = -1e30f;
    for (int j = tid; j < kN; j += 256) {
        if (adj[i * kN + j] > 0) {
            float e = s1i + s2[j];
            e = e > 0.f ? e : 0.01f * e;
            m = fmaxf(m, e);
        }
    }
    red[tid] = m; __syncthreads();
    for (int s = 128; s > 0; s >>= 1) { if (tid < s) red[tid] = fmaxf(red[tid], red[tid + s]); __syncthreads(); }
    if (tid == 0) sh_m = red[0];
    __syncthreads();
    m = sh_m;
    float sum = 0.f;
    for (int j = tid; j < kN; j += 256) {
        if (adj[i * kN + j] > 0) {
            float e = s1i + s2[j];
            e = e > 0.f ? e : 0.01f * e;
            sum += expf(e - m);
        }
    }
    red[tid] = sum; __syncthreads();
    for (int s = 128; s > 0; s >>= 1) { if (tid < s) red[tid] += red[tid + s]; __syncthreads(); }
    if (tid == 0) sh_s = red[0];
    __syncthreads();
    float inv = sh_s > 0.f ? 1.f / sh_s : 0.f;
    for (int j = tid; j < kN; j += 256) {
        float v = 0.f;
        if (adj[i * kN + j] > 0) {
            float e = s1i + s2[j];
            e = e > 0.f ? e : 0.01f * e;
            v = expf(e - m) * inv;
        }
        att[(size_t)i * 352 + j] = __float2bfloat16(v);
    }
}

__global__ void build_cat4(const float* __restrict__ hs2, bf16* __restrict__ cat4) {
    int idx = blockIdx.x * 256 + threadIdx.x;
    if (idx >= kN * 4800) return;
    int r = idx / 4800, c = idx - r * 4800;
    int chunk = c / kG, cc = c - chunk * kG;
    float hc = hs2[cc];
    float hv = hs2[(size_t)r * kG + cc];
    float v = (chunk == 0) ? hc : (chunk == 1) ? hv : (chunk == 2) ? hc * hv : (hc - hv);
    cat4[idx] = __float2bfloat16(v);
}

__global__ void row_dot_tanh(const float* __restrict__ hc3, const float* __restrict__ FC2,
                             float* __restrict__ b_att) {
    __shared__ float red[256];
    int n = blockIdx.x, tid = threadIdx.x;
    float d = 0.f;
    for (int c = tid; c < 9600; c += 256) d += hc3[(size_t)n * 9600 + c] * FC2[c];
    red[tid] = d; __syncthreads();
    for (int s = 128; s > 0; s >>= 1) { if (tid < s) red[tid] += red[tid + s]; __syncthreads(); }
    if (tid == 0) b_att[n] = tanhf(red[0]);
}

__global__ void ea_kernel(const float* __restrict__ hs2, const float* __restrict__ b_att,
                          float* __restrict__ ea) {
    int c = blockIdx.x * 256 + threadIdx.x;
    if (c >= kG) return;
    float s = 0.f, w = 0.f;
    for (int r = 0; r < kN; ++r) {
        float v = hs2[(size_t)r * kG + c];
        s += v;
        w += b_att[r] * v;
    }
    ea[c] = s / (float)kN;
    ea[kG + c] = w;
}

__global__ void final_kernel(const float* __restrict__ ea, const float* __restrict__ Wlin,
                             const float* __restrict__ blin, float* __restrict__ out) {
    __shared__ float red[256];
    int tid = threadIdx.x;
    float l0 = 0.f, l1 = 0.f;
    for (int c = tid; c < 2400; c += 256) {
        float e = ea[c];
        l0 += e * Wlin[c];
        l1 += e * Wlin[2400 + c];
    }
    red[tid] = l0; __syncthreads();
    for (int s = 128; s > 0; s >>= 1) { if (tid < s) red[tid] += red[tid + s]; __syncthreads(); }
    l0 = red[0]; __syncthreads();
    red[tid] = l1; __syncthreads();
    for (int s = 128; s > 0; s >>= 1) { if (tid < s) red[tid] += red[tid + s]; __syncthreads(); }
    l1 = red[0];
    if (tid == 0) {
        l0 += blin[0];
        l1 += blin[1];
        float m = fmaxf(l0, l1);
        float e0 = expf(l0 - m), e1 = expf(l1 - m);
        float inv = 1.f / (e0 + e1);
        out[0] = e0 * inv;
        out[1] = e1 * inv;
    }
}

// ---------------------------------------------------------------------------
extern "C" void kernel_launch(void* const* d_in, const int* in_sizes, int n_in,
                              void* d_out, int out_size, void* d_ws, size_t ws_size,
                              hipStream_t stream) {
    const int*   tokens  = (const int*)d_in[0];
    const int*   adj     = (const int*)d_in[1];
    const float* emb     = (const float*)d_in[2];
    const float* Wih_l0f = (const float*)d_in[3];
    const float* Whh_l0f = (const float*)d_in[4];
    const float* b_l0f   = (const float*)d_in[5];
    const float* Wih_l0b = (const float*)d_in[6];
    const float* Whh_l0b = (const float*)d_in[7];
    const float* b_l0b   = (const float*)d_in[8];
    const float* Wih_l1f = (const float*)d_in[9];
    const float* Whh_l1f = (const float*)d_in[10];
    const float* b_l1f   = (const float*)d_in[11];
    const float* Wih_l1b = (const float*)d_in[12];
    const float* Whh_l1b = (const float*)d_in[13];
    const float* b_l1b   = (const float*)d_in[14];
    const float* W_gat   = (const float*)d_in[15];
    const float* a_gat   = (const float*)d_in[16];
    const float* gate_W  = (const float*)d_in[17];
    const float* gate_U  = (const float*)d_in[18];
    const float* FC1     = (const float*)d_in[19];
    const float* FC2     = (const float*)d_in[20];
    const float* Wlin    = (const float*)d_in[21];
    const float* blin    = (const float*)d_in[22];
    float* out = (float*)d_out;
    (void)in_sizes; (void)n_in; (void)out_size; (void)ws_size;

    char* base = (char*)d_ws;
    size_t off = 0;
    auto alloc = [&](size_t bytes) {
        size_t cur = off;
        off += (bytes + 255) & ~(size_t)255;
        return base + cur;
    };

    // Region A with phase overlays:
    //   phase 1: [xPad 11.1MB | P0 83MB]
    //   phase 2: [P1 83MB] (x,P0 dead)
    //   phase 3: [WgatT 6.1 | hin 1.8 | att 0.27] (P1 dead)
    //   phase 4: [FC1T 92.2MB] (GAT scratch dead)
    const size_t xPad_sz = (size_t)kNLp * kKp0 * 2;         // 11,141,120
    const size_t P_sz    = (size_t)2 * kNL * kG * 2;        // 83,040,000
    char* regA = alloc(94181120);
    bf16* xPad  = (bf16*)(regA);
    bf16* P0    = (bf16*)(regA + xPad_sz);
    bf16* P1    = (bf16*)(regA);
    bf16* WgatT = (bf16*)(regA);                 // 1280*2400*2 = 6,144,000
    bf16* hin   = (bf16*)(regA + 6144000);       // 384*2400*2  = 1,843,200
    bf16* att   = (bf16*)(regA + 7987200);       // 384*352*2   =   270,336
    bf16* FC1T  = (bf16*)(regA);                 // 9600*4800*2 = 92,160,000
    const size_t gatScratch_sz = 8257536;
    (void)P_sz;

    // o0 region, later overlaid by hc3
    char* o0r   = alloc((size_t)kNLp * kKp1 * 2);            // 21,168,128
    bf16*  o0   = (bf16*)o0r;
    float* hc3  = (float*)o0r;                               // 346*9600*4 = 13,286,400

    float* g    = (float*)alloc((size_t)2 * kN * kG * 4);
    // contiguous zero-init block: c0,c1 fp32 + hbf0,hbf1 bf16
    char* stateblk = alloc(2 * 830400 + 2 * 491520);
    float* c0   = (float*)(stateblk);
    float* c1   = (float*)(stateblk + 830400);
    bf16*  hbf0 = (bf16*)(stateblk + 2 * 830400);
    bf16*  hbf1 = (bf16*)(stateblk + 2 * 830400 + 491520);
    const size_t state_sz = 2 * 830400 + 2 * 491520;

    bf16* Wih0 = (bf16*)alloc((size_t)2 * kGp * kKp0 * 2);
    bf16* Wih1 = (bf16*)alloc((size_t)2 * kGp * kKp1 * 2);
    bf16* Whh0 = (bf16*)alloc((size_t)2 * kGp * kKp0 * 2);
    bf16* Whh1 = (bf16*)alloc((size_t)2 * kGp * kKp0 * 2);
    float* b0p = (float*)alloc(2400 * 4);
    float* b1p = (float*)alloc(2400 * 4);
    float* hsA = (float*)alloc((size_t)kN * kG * 4);
    float* hsB = (float*)alloc((size_t)kN * kG * 4);
    float* sum_hx = (float*)alloc(kG * 4);
    float* Wh  = (float*)alloc((size_t)kN * kG * 4);
    bf16*  WhT = (bf16*)alloc((size_t)kGp * 352 * 2);
    float* s1  = (float*)alloc(kN * 4);
    float* s2  = (float*)alloc(kN * 4);
    bf16*  cat4 = (bf16*)alloc((size_t)kNp * 4800 * 2);
    float* b_att = (float*)alloc(kN * 4);
    float* ea  = (float*)alloc(2400 * 4);

    // ---- init (every call: ws is re-poisoned) ----
    hipMemsetAsync(stateblk, 0, state_sz, stream);
    hipMemsetAsync(o0r, 0, (size_t)kNLp * kKp1 * 2, stream);
    hipMemsetAsync(cat4, 0, (size_t)kNp * 4800 * 2, stream);

    // ---- weight prep ----
    pack_biases<<<10, 256, 0, stream>>>(b_l0f, b_l0b, b_l1f, b_l1b, b0p, b1p);
    int cpb0 = (kGp * kKp0 + 255) / 256;  // 1280x320
    int cpb1 = (kGp * kKp1 + 255) / 256;  // 1280x608
    convert_pad<<<cpb0, 256, 0, stream>>>(Wih_l0f, Wih0,              kG, kD,     kGp, kKp0);
    convert_pad<<<cpb0, 256, 0, stream>>>(Wih_l0b, Wih0 + kGp * kKp0, kG, kD,     kGp, kKp0);
    convert_pad<<<cpb1, 256, 0, stream>>>(Wih_l1f, Wih1,              kG, 2 * kH, kGp, kKp1);
    convert_pad<<<cpb1, 256, 0, stream>>>(Wih_l1b, Wih1 + kGp * kKp1, kG, 2 * kH, kGp, kKp1);
    convert_pad<<<cpb0, 256, 0, stream>>>(Whh_l0f, Whh0,              kG, kH,     kGp, kKp0);
    convert_pad<<<cpb0, 256, 0, stream>>>(Whh_l0b, Whh0 + kGp * kKp0, kG, kH,     kGp, kKp0);
    convert_pad<<<cpb0, 256, 0, stream>>>(Whh_l1f, Whh1,              kG, kH,     kGp, kKp0);
    convert_pad<<<cpb0, 256, 0, stream>>>(Whh_l1b, Whh1 + kGp * kKp0, kG, kH,     kGp, kKp0);

    // ---- embedding gather ----
    gather_kernel<<<(kNLp * kKp0 + 255) / 256, 256, 0, stream>>>(tokens, emb, xPad);

    // ---- layer-0 input projections (z=dir) ----
    gemm_mfma<0, bf16><<<dim3(10, kNLp / 128, 2), 256, 0, stream>>>(
        xPad, Wih0, P0, kNL, kG, kKp0, kKp0, kKp0, kG,
        0, (long)kGp * kKp0, (long)kNL * kG, nullptr, 0, nullptr, 0);

    // ---- layer-0 scan ----
    const long sC = (long)kN * kG;
    int ptBlocks = (2 * kN * kH + 255) / 256;
    for (int t = 0; t < kL; ++t) {
        long sP = (long)kNL * kG + (long)(kL - 1 - 2 * t) * kN * kG;
        gemm_mfma<1, float><<<dim3(10, 3, 2), 256, 0, stream>>>(
            hbf0, Whh0, g, kN, kG, kKp0, kKp0, kKp0, kG,
            (long)kNp * kKp0, (long)kGp * kKp0, sC,
            P0 + (size_t)t * kN * kG, sP, b0p, 1200);
        lstm_point<<<ptBlocks, 256, 0, stream>>>(g, c0, hbf0, o0, t, kL - 1 - t);
    }

    // ---- layer-1 input projections (P1 overlays dead xPad/P0) ----
    gemm_mfma<0, bf16><<<dim3(10, kNLp / 128, 2), 256, 0, stream>>>(
        o0, Wih1, P1, kNL, kG, kKp1, kKp1, kKp1, kG,
        0, (long)kGp * kKp1, (long)kNL * kG, nullptr, 0, nullptr, 0);

    // ---- layer-1 scan ----
    for (int t = 0; t < kL; ++t) {
        long sP = (long)kNL * kG + (long)(kL - 1 - 2 * t) * kN * kG;
        gemm_mfma<1, float><<<dim3(10, 3, 2), 256, 0, stream>>>(
            hbf1, Whh1, g, kN, kG, kKp0, kKp0, kKp0, kG,
            (long)kNp * kKp0, (long)kGp * kKp0, sC,
            P1 + (size_t)t * kN * kG, sP, b1p, 1200);
        lstm_point<<<ptBlocks, 256, 0, stream>>>(g, c1, hbf1, (bf16*)nullptr, t, kL - 1 - t);
    }

    // ---- hs0 = [hf0, hb0, hf1, hb1] ----
    concat_hs0<<<(kN * kG + 255) / 256, 256, 0, stream>>>(hbf0, hbf1, hsA);

    // ---- GAT scratch (overlays dead P1); zero pads then fill WgatT ----
    hipMemsetAsync(regA, 0, gatScratch_sz, stream);
    transpose_conv<<<dim3(kGp / 32, 2400 / 32), 256, 0, stream>>>(W_gat, WgatT, 2400, kG, 2400, kGp);

    float* hsIn = hsA;
    float* hsOut = hsB;
    for (int it = 0; it < 2; ++it) {
        colsum_kernel<<<(kG + 255) / 256, 256, 0, stream>>>(hsIn, sum_hx);
        gate_rows<<<kN, 256, 0, stream>>>(hsIn, gate_W, gate_U, sum_hx, hin);
        gemm_mfma<0, float><<<dim3(10, 3, 1), 256, 0, stream>>>(
            hin, WgatT, Wh, kN, kG, 2400, 2400, 2400, kG,
            0, 0, 0, nullptr, 0, nullptr, 0);
        gat_scores<<<kN, 256, 0, stream>>>(Wh, a_gat, s1, s2);
        gat_softmax<<<kN, 256, 0, stream>>>(s1, s2, adj, att);
        transpose_conv<<<dim3(kGp / 32, 352 / 32), 256, 0, stream>>>(Wh, WhT, kN, kG, 352, kGp);
        gemm_mfma<3, float><<<dim3(10, 3, 1), 256, 0, stream>>>(
            att, WhT, hsOut, kN, kG, 352, 352, 352, kG,
            0, 0, 0, nullptr, 0, nullptr, 0);
        float* tmp = hsIn; hsIn = hsOut; hsOut = tmp;
    }
    // hs2 = hsIn

    // ---- head ----
    build_cat4<<<(kN * 4800 + 255) / 256, 256, 0, stream>>>(hsIn, cat4);
    transpose_conv<<<dim3(9600 / 32, 4800 / 32), 256, 0, stream>>>(FC1, FC1T, 4800, 9600, 4800, 9600);
    gemm_mfma<4, float><<<dim3(75, 3, 1), 256, 0, stream>>>(
        cat4, FC1T, hc3, kN, 9600, 4800, 4800, 4800, 9600,
        0, 0, 0, nullptr, 0, nullptr, 0);
    row_dot_tanh<<<kN, 256, 0, stream>>>(hc3, FC2, b_att);
    ea_kernel<<<(kG + 255) / 256, 256, 0, stream>>>(hsIn, b_att, ea);
    final_kernel<<<1, 256, 0, stream>>>(ea, Wlin, blin, out);
}